// Round 12
// baseline (89.570 us; speedup 1.0000x reference)
//
#include <hip/hip_runtime.h>

typedef short s16x4 __attribute__((ext_vector_type(4)));
typedef short s16x8 __attribute__((ext_vector_type(8)));
typedef float f32x4 __attribute__((ext_vector_type(4)));
typedef unsigned int u32;

#define DEV static __device__ __forceinline__

// B=4, S=2048, D=512, H=8, DK=64, M = B*S = 8192

DEV unsigned short f2bf(float f) {
    unsigned u = __float_as_uint(f);
    u += 0x7FFFu + ((u >> 16) & 1u);   // RNE round to bf16
    return (unsigned short)(u >> 16);
}

DEV u32 cvtpk(float lo, float hi) {
    u32 r;
    asm("v_cvt_pk_bf16_f32 %0, %1, %2" : "=v"(r) : "v"(lo), "v"(hi));
    return r;
}
DEV void pl32swap(u32& a, u32& b) {
    asm("v_permlane32_swap_b32 %0, %1" : "+v"(a), "+v"(b));
}
DEV void pl16swap(u32& a, u32& b) {
    asm("v_permlane16_swap_b32 %0, %1" : "+v"(a), "+v"(b));
}
DEV void gl16(const void* g, void* l) {
    __builtin_amdgcn_global_load_lds((const __attribute__((address_space(1))) u32*)g,
                                     (__attribute__((address_space(3))) u32*)l, 16, 0, 0);
}

// ---------------- fused LayerNorm + weight convert ----------------
__global__ __launch_bounds__(256) void lnw_kernel(const float* __restrict__ x,
        const float* __restrict__ gamma, const float* __restrict__ beta,
        unsigned short* __restrict__ xn,
        const float* __restrict__ wq, const float* __restrict__ wk,
        const float* __restrict__ wv, const float* __restrict__ wo,
        unsigned short* __restrict__ wdst)
{
    if (blockIdx.x >= 2048) {
        int idx = blockIdx.x - 2048;
        int m = idx >> 6, sub = idx & 63;
        const float* src = (m == 0) ? wq : (m == 1) ? wk : (m == 2) ? wv : wo;
        unsigned short* d = wdst + (size_t)m * 262144;
        const f32x4* s4 = (const f32x4*)src;
        s16x4* d4 = (s16x4*)d;
#pragma unroll
        for (int i = 0; i < 4; ++i) {
            int e = sub * 1024 + i * 256 + threadIdx.x;
            f32x4 v = s4[e];
            s16x4 o;
            o[0] = f2bf(v[0]); o[1] = f2bf(v[1]); o[2] = f2bf(v[2]); o[3] = f2bf(v[3]);
            d4[e] = o;
        }
        return;
    }
    int t = threadIdx.x, w = t >> 6, lane = t & 63;
    int row = blockIdx.x * 4 + w;
    const float* xr = x + (size_t)row * 512 + lane * 8;
    f32x4 v0 = *(const f32x4*)xr;
    f32x4 v1 = *(const f32x4*)(xr + 4);
    float s = 0.f, s2 = 0.f;
#pragma unroll
    for (int i = 0; i < 4; ++i) { s += v0[i] + v1[i]; s2 += v0[i] * v0[i] + v1[i] * v1[i]; }
#pragma unroll
    for (int m = 1; m < 64; m <<= 1) { s += __shfl_xor(s, m); s2 += __shfl_xor(s2, m); }
    float mu = s * (1.f / 512.f);
    float var = s2 * (1.f / 512.f) - mu * mu;
    float rstd = rsqrtf(var + 1e-5f);
    f32x4 g0 = *(const f32x4*)(gamma + lane * 8);
    f32x4 g1 = *(const f32x4*)(gamma + lane * 8 + 4);
    f32x4 b0 = *(const f32x4*)(beta + lane * 8);
    f32x4 b1 = *(const f32x4*)(beta + lane * 8 + 4);
    s16x8 o;
#pragma unroll
    for (int i = 0; i < 4; ++i) {
        o[i]     = f2bf((v0[i] - mu) * rstd * g0[i] + b0[i]);
        o[i + 4] = f2bf((v1[i] - mu) * rstd * g1[i] + b1[i]);
    }
    *(s16x8*)(xn + (size_t)row * 512 + lane * 8) = o;
}

// ---------------- pipelined 128x128 GEMM core (BK=32, 3-buf, depth-2 prefetch) ----------------
#define GEMM_PIPE(APTR, BPTR, ACC) do { \
    int bc_ = 0, bs_ = 2; \
    STAGE(0, 0); STAGE(1, 1); \
    for (int it_ = 0; it_ < 16; ++it_) { \
        asm volatile("" ::: "memory"); \
        __builtin_amdgcn_s_barrier(); \
        if (it_ + 2 < 16) { \
            STAGE(it_ + 2, bs_); \
            asm volatile("s_waitcnt vmcnt(8)" ::: "memory"); \
        } else if (it_ + 1 < 16) { \
            asm volatile("s_waitcnt vmcnt(4)" ::: "memory"); \
        } else { \
            asm volatile("s_waitcnt vmcnt(0)" ::: "memory"); \
        } \
        __builtin_amdgcn_s_barrier(); \
        asm volatile("" ::: "memory"); \
        const char* Ab_ = (const char*)(APTR) + bc_ * 8192; \
        const char* Bb_ = (const char*)(BPTR) + bc_ * 8192; \
        s16x8 af_[4], bf_[4]; \
        _Pragma("unroll") \
        for (int i_ = 0; i_ < 4; ++i_) { \
            af_[i_] = *(const s16x8*)(Ab_ + (wm * 64 + i_ * 16 + l15) * 64 + swz); \
            bf_[i_] = *(const s16x8*)(Bb_ + (wn * 64 + i_ * 16 + l15) * 64 + swz); \
        } \
        __builtin_amdgcn_s_setprio(1); \
        _Pragma("unroll") \
        for (int i_ = 0; i_ < 4; ++i_) \
            _Pragma("unroll") \
            for (int j_ = 0; j_ < 4; ++j_) \
                ACC[i_][j_] = __builtin_amdgcn_mfma_f32_16x16x32_bf16(af_[i_], bf_[j_], ACC[i_][j_], 0, 0, 0); \
        __builtin_amdgcn_s_setprio(0); \
        bc_ = (bc_ == 2) ? 0 : bc_ + 1; \
        bs_ = (bs_ == 2) ? 0 : bs_ + 1; \
    } \
} while (0)

// ---------------- QKV projection GEMM ----------------
// z=0 -> Q frag-major ; z=1 -> K frag-major ; z=2 -> V frag-major
// K[s][dk]: ((bh*32+tile)*8 + kf*2+ks)*512 + (g*16+l15)*8+e   (tile=s>>6,kf=(s>>4)&3,l15=s&15; ks=dk>>5,g=(dk>>3)&3,e=dk&7)
// V[s][dk]: ((bh*32+tile)*8 + nf*2+half)*512 + (g*16+l15v)*8+e (nf=dk>>4,l15v=dk&15; half=(s>>5)&1,g=(s>>3)&3,e=s&7)
// Q[s][dk]: ((bh*64+qt)*4 + qf*2+ks)*512 + (g*16+l15q)*8+e    (qt=s>>5,qf=(s>>4)&1,l15q=s&15; ks=dk>>5,g=(dk>>3)&3,e=dk&7)
__global__ __launch_bounds__(256, 3) void qkv_kernel(const unsigned short* __restrict__ xn,
        const unsigned short* __restrict__ wbase,
        const float* __restrict__ bq, const float* __restrict__ bk, const float* __restrict__ bv,
        unsigned short* __restrict__ qo, unsigned short* __restrict__ kfm,
        unsigned short* __restrict__ vfm)
{
    __shared__ __align__(16) unsigned short As[3][128 * 32];
    __shared__ __align__(16) unsigned short Bs[3][128 * 32];
    int z = blockIdx.z;
    const unsigned short* W = wbase + (size_t)z * 262144;
    const float* bias = (z == 0) ? bq : (z == 1) ? bk : bv;

    int t = threadIdx.x, lane = t & 63, w = t >> 6;
    int g = lane >> 4, l15 = lane & 15;
    int wm = w >> 1, wn = w & 1;
    int mBase = blockIdx.x * 128, nBase = blockIdx.y * 128;

    int srow = t >> 2;
    int scol = ((t & 3) ^ ((t >> 2) & 3) ^ ((t >> 4) & 3)) * 8;
    const unsigned short* ag = xn + (size_t)(mBase + srow) * 512 + scol;
    const unsigned short* bg = W + (size_t)(nBase + srow) * 512 + scol;
    int swz = ((g ^ (l15 & 3) ^ ((l15 >> 2) & 3))) * 16;

    f32x4 acc[4][4] = {};

#define STAGE(it_, buf_) do { \
        int k0_ = (it_) * 32; \
        gl16(ag + k0_,          (char*)&As[buf_][0] + t * 16); \
        gl16(ag + 32768 + k0_,  (char*)&As[buf_][0] + t * 16 + 4096); \
        gl16(bg + k0_,          (char*)&Bs[buf_][0] + t * 16); \
        gl16(bg + 32768 + k0_,  (char*)&Bs[buf_][0] + t * 16 + 4096); \
    } while (0)

    GEMM_PIPE(&As[0][0], &Bs[0][0], acc);
#undef STAGE

#pragma unroll
    for (int i = 0; i < 4; ++i) {
        int row0 = mBase + wm * 64 + i * 16 + g * 4;
        int bb = row0 >> 11;
        int s0 = row0 & 2047;
#pragma unroll
        for (int j = 0; j < 4; ++j) {
            int col = nBase + wn * 64 + j * 16 + l15;
            float bia = bias[col];
            int h = col >> 6, dk = col & 63;
            int bh = bb * 8 + h;
            if (z == 0) {
                float sc = 0.18033688011112042f;   // 0.125*log2(e)
                int ks = dk >> 5, gq = (dk >> 3) & 3, e = dk & 7;
                int qt2 = s0 >> 5, qf2 = (s0 >> 4) & 1;
                size_t base = (((size_t)bh * 64 + qt2) * 4 + qf2 * 2 + ks) * 512 + (gq * 16 + (s0 & 15)) * 8 + e;
#pragma unroll
                for (int r = 0; r < 4; ++r)
                    qo[base + r * 8] = f2bf((acc[i][j][r] + bia) * sc);
            } else if (z == 1) {
                int ks = dk >> 5, gg = (dk >> 3) & 3, e = dk & 7;
                int tile = s0 >> 6, kf = (s0 >> 4) & 3, l0 = s0 & 15;
                size_t base = ((size_t)bh * 32 + tile) * 4096 + (kf * 2 + ks) * 512 + (gg * 16 + l0) * 8 + e;
#pragma unroll
                for (int r = 0; r < 4; ++r)
                    kfm[base + r * 8] = f2bf(acc[i][j][r] + bia);
            } else {
                int nf = dk >> 4, l0v = dk & 15;
                int tile = s0 >> 6, half = (s0 >> 5) & 1, gg = (s0 >> 3) & 3, e0 = s0 & 7;
                size_t base = ((size_t)bh * 32 + tile) * 4096 + (nf * 2 + half) * 512 + (gg * 16 + l0v) * 8 + e0;
                s16x4 pk;
#pragma unroll
                for (int r = 0; r < 4; ++r) pk[r] = f2bf(acc[i][j][r] + bia);
                *(s16x4*)(vfm + base) = pk;
            }
        }
    }
}

// ---------------- flash attention: barrier-free 1-wave blocks, all operands frag-major ----------------
// grid 4096, 64 thr. Decode: h=lin&7 (per-XCD K/V 2MB L2-resident), b=(lin>>3)&3,
// split=(lin>>5)&1 (parity-interleaved tiles -> balanced), qt=lin>>6 (32 q-rows).
// 16 blocks/CU = 4 waves/SIMD, zero barriers: each wave's load stalls are private
// and covered by 3 peer waves. K/V frag loads = coalesced 1KB wave-loads from L1/L2.
__global__ __launch_bounds__(64, 4) void attn_kernel(const unsigned short* __restrict__ qfm,
        const unsigned short* __restrict__ kfm, const unsigned short* __restrict__ vfm,
        const int* __restrict__ lens, unsigned short* __restrict__ o_part, float* __restrict__ l_part)
{
    int lane = threadIdx.x & 63;
    int g = lane >> 4, l15 = lane & 15;
    int lin = blockIdx.x;
    int h = lin & 7;
    int b = (lin >> 3) & 3;
    int split = (lin >> 5) & 1;
    int qt = lin >> 6;                 // 0..63
    int bh = b * 8 + h;
    int qb = qt * 32;
    int len = lens[b];
    int ntf = (len + 63) >> 6;
    int ntX = (ntf - split + 1) >> 1;  // tiles with parity `split`

    const unsigned short* kbh = kfm + (size_t)bh * 131072;
    const unsigned short* vbh = vfm + (size_t)bh * 131072;

    s16x8 qf_[2][2];
    {
        const unsigned short* qp = qfm + ((size_t)bh * 64 + qt) * 2048 + lane * 8;
#pragma unroll
        for (int qf = 0; qf < 2; ++qf)
#pragma unroll
            for (int ks = 0; ks < 2; ++ks)
                qf_[qf][ks] = *(const s16x8*)(qp + (qf * 2 + ks) * 512);
    }

    s16x8 ones;
#pragma unroll
    for (int i = 0; i < 8; ++i) ones[i] = (short)0x3F80;   // bf16 1.0

    f32x4 oacc[2][4] = {};   // [qf][nf]
    f32x4 sacc[2] = {};

    for (int li = 0; li < ntX; ++li) {
        int tt = split + li * 2;
        int kb = tt << 6;
        const unsigned short* kt = kbh + (size_t)tt * 4096 + lane * 8;
        const unsigned short* vt_ = vbh + (size_t)tt * 4096 + lane * 8;

        // QK^T -> S^T: sa[kf][qf]; k-row = kf*16 + g*4 + r. kfr scoped per ks (VGPR discipline).
        f32x4 sa[4][2] = {};
#pragma unroll
        for (int ks = 0; ks < 2; ++ks) {
            s16x8 kfr[4];
#pragma unroll
            for (int kf = 0; kf < 4; ++kf)
                kfr[kf] = *(const s16x8*)(kt + (kf * 2 + ks) * 512);
            __builtin_amdgcn_s_setprio(1);
#pragma unroll
            for (int kf = 0; kf < 4; ++kf)
#pragma unroll
                for (int qf = 0; qf < 2; ++qf)
                    sa[kf][qf] = __builtin_amdgcn_mfma_f32_16x16x32_bf16(kfr[kf], qf_[qf][ks], sa[kf][qf], 0, 0, 0);
            __builtin_amdgcn_s_setprio(0);
        }

        if (kb + 64 > len) {
            const float NEG = -__builtin_huge_valf();
#pragma unroll
            for (int kf = 0; kf < 4; ++kf)
#pragma unroll
                for (int r = 0; r < 4; ++r)
                    if (kb + kf * 16 + g * 4 + r >= len) { sa[kf][0][r] = NEG; sa[kf][1][r] = NEG; }
        }

        // two k-halves: V frag loads issued first (latency hides under exp2 chain),
        // then exp2 (fixed-max, scale folded into q) -> permlane P -> PV + ones row-sum
#pragma unroll
        for (int half = 0; half < 2; ++half) {
            s16x8 vbf[4];
#pragma unroll
            for (int nf = 0; nf < 4; ++nf)
                vbf[nf] = *(const s16x8*)(vt_ + (nf * 2 + half) * 512);
            u32 pkd[2][2][2];
#pragma unroll
            for (int qf = 0; qf < 2; ++qf)
#pragma unroll
                for (int k2 = 0; k2 < 2; ++k2) {
                    int kf = half * 2 + k2;
#pragma unroll
                    for (int r = 0; r < 4; ++r)
                        sa[kf][qf][r] = __builtin_amdgcn_exp2f(sa[kf][qf][r]);
                    pkd[k2][qf][0] = cvtpk(sa[kf][qf][0], sa[kf][qf][1]);
                    pkd[k2][qf][1] = cvtpk(sa[kf][qf][2], sa[kf][qf][3]);
                }
            __builtin_amdgcn_s_setprio(1);
#pragma unroll
            for (int qf = 0; qf < 2; ++qf) {
                u32 a0 = pkd[0][qf][0], b0 = pkd[1][qf][0];
                u32 a1 = pkd[0][qf][1], b1 = pkd[1][qf][1];
                pl32swap(a0, b0); pl16swap(a0, b0);
                pl32swap(a1, b1); pl16swap(a1, b1);
                union { u32 d[4]; s16x8 v; } pf;
                pf.d[0] = a0; pf.d[1] = a1; pf.d[2] = b0; pf.d[3] = b1;
                sacc[qf] = __builtin_amdgcn_mfma_f32_16x16x32_bf16(pf.v, ones, sacc[qf], 0, 0, 0);
#pragma unroll
                for (int nf = 0; nf < 4; ++nf)
                    oacc[qf][nf] = __builtin_amdgcn_mfma_f32_16x16x32_bf16(pf.v, vbf[nf], oacc[qf][nf], 0, 0, 0);
            }
            __builtin_amdgcn_s_setprio(0);
        }
    }

    // write bf16 unnormalized O partial + fp32 l partial
    unsigned short* op = o_part + (size_t)split * (8192 * 512);
#pragma unroll
    for (int qf = 0; qf < 2; ++qf)
#pragma unroll
        for (int r = 0; r < 4; ++r) {
            int s = qb + qf * 16 + g * 4 + r;
#pragma unroll
            for (int nf = 0; nf < 4; ++nf)
                op[(size_t)(b * 2048 + s) * 512 + h * 64 + nf * 16 + l15] = f2bf(oacc[qf][nf][r]);
        }
    float* lp = l_part + split * 65536 + bh * 2048;
    if (l15 == 0) {
#pragma unroll
        for (int qf = 0; qf < 2; ++qf)
#pragma unroll
            for (int r = 0; r < 4; ++r)
                lp[qb + qf * 16 + g * 4 + r] = sacc[qf][r];
    }
}

// ---------------- combine: (O0+O1)/(l0+l1) -> bf16 ----------------
__global__ __launch_bounds__(256) void comb_kernel(const unsigned short* __restrict__ o_part,
        const float* __restrict__ l_part, unsigned short* __restrict__ A)
{
    int e0 = (blockIdx.x * 256 + threadIdx.x) * 8;
    int row = e0 >> 9, col0 = e0 & 511;
    int b = row >> 11, s = row & 2047, h = col0 >> 6;
    s16x8 u0 = *(const s16x8*)(o_part + (size_t)row * 512 + col0);
    s16x8 u1 = *(const s16x8*)(o_part + (size_t)(8192 + row) * 512 + col0);
    float l = l_part[(b * 8 + h) * 2048 + s] + l_part[65536 + (b * 8 + h) * 2048 + s];
    float inv = 1.f / l;
    s16x8 o;
#pragma unroll
    for (int i = 0; i < 8; ++i) {
        float f0 = __uint_as_float(((u32)(unsigned short)u0[i]) << 16);
        float f1 = __uint_as_float(((u32)(unsigned short)u1[i]) << 16);
        o[i] = f2bf((f0 + f1) * inv);
    }
    *(s16x8*)(A + (size_t)row * 512 + col0) = o;
}

// ---------------- output projection GEMM (fp32 out) ----------------
__global__ __launch_bounds__(256, 3) void oproj_kernel(const unsigned short* __restrict__ A,
        const unsigned short* __restrict__ W, const float* __restrict__ bo,
        float* __restrict__ out)
{
    __shared__ __align__(16) unsigned short As[3][128 * 32];
    __shared__ __align__(16) unsigned short Bs[3][128 * 32];
    int t = threadIdx.x, lane = t & 63, w = t >> 6;
    int g = lane >> 4, l15 = lane & 15;
    int wm = w >> 1, wn = w & 1;
    int mBase = blockIdx.x * 128, nBase = blockIdx.y * 128;

    int srow = t >> 2;
    int scol = ((t & 3) ^ ((t >> 2) & 3) ^ ((t >> 4) & 3)) * 8;
    const unsigned short* ag = A + (size_t)(mBase + srow) * 512 + scol;
    const unsigned short* bg = W + (size_t)(nBase + srow) * 512 + scol;
    int swz = ((g ^ (l15 & 3) ^ ((l15 >> 2) & 3))) * 16;

    f32x4 acc[4][4] = {};

#define STAGE(it_, buf_) do { \
        int k0_ = (it_) * 32; \
        gl16(ag + k0_,          (char*)&As[buf_][0] + t * 16); \
        gl16(ag + 32768 + k0_,  (char*)&As[buf_][0] + t * 16 + 4096); \
        gl16(bg + k0_,          (char*)&Bs[buf_][0] + t * 16); \
        gl16(bg + 32768 + k0_,  (char*)&Bs[buf_][0] + t * 16 + 4096); \
    } while (0)

    GEMM_PIPE(&As[0][0], &Bs[0][0], acc);
#undef STAGE

#pragma unroll
    for (int i = 0; i < 4; ++i) {
        int row0 = mBase + wm * 64 + i * 16 + g * 4;
#pragma unroll
        for (int j = 0; j < 4; ++j) {
            int col = nBase + wn * 64 + j * 16 + l15;
            float bia = bo[col];
#pragma unroll
            for (int r = 0; r < 4; ++r)
                out[(size_t)(row0 + r) * 512 + col] = acc[i][j][r] + bia;
        }
    }
}

extern "C" void kernel_launch(void* const* d_in, const int* in_sizes, int n_in,
                              void* d_out, int out_size, void* d_ws, size_t ws_size,
                              hipStream_t stream) {
    (void)in_sizes; (void)n_in; (void)out_size; (void)ws_size;
    const float* x     = (const float*)d_in[0];
    const int*   lens  = (const int*)d_in[1];
    // d_in[2] = pos_embed (unused by reference)
    const float* gamma = (const float*)d_in[3];
    const float* beta  = (const float*)d_in[4];
    const float* Wq = (const float*)d_in[5];
    const float* bq = (const float*)d_in[6];
    const float* Wk = (const float*)d_in[7];
    const float* bk = (const float*)d_in[8];
    const float* Wv = (const float*)d_in[9];
    const float* bv = (const float*)d_in[10];
    const float* Wo = (const float*)d_in[11];
    const float* bo = (const float*)d_in[12];

    char* ws = (char*)d_ws;
    unsigned short* wbf = (unsigned short*)(ws);                  // 0..2MB: 4x512x512 bf16
    unsigned short* xn  = (unsigned short*)(ws + (2ull  << 20));  // 2..10MB: LN out / attn-combined (oproj A)
    unsigned short* qfm = (unsigned short*)(ws + (10ull << 20));  // Q frag-major
    unsigned short* kfm = (unsigned short*)(ws + (18ull << 20));  // K frag-major
    unsigned short* vfm = (unsigned short*)(ws + (26ull << 20));  // V frag-major
    unsigned short* o_part = (unsigned short*)(ws + (34ull << 20)); // 34..50MB: [2][8192][512] bf16
    float* l_part = (float*)(ws + (50ull << 20));                 // 50..50.5MB: [2][32][2048] f32
    float* out = (float*)d_out;

    lnw_kernel<<<2304, 256, 0, stream>>>(x, gamma, beta, xn, Wq, Wk, Wv, Wo, wbf);
    qkv_kernel<<<dim3(64, 4, 3), 256, 0, stream>>>(xn, wbf, bq, bk, bv, qfm, kfm, vfm);
    attn_kernel<<<4096, 64, 0, stream>>>(qfm, kfm, vfm, lens, o_part, l_part);
    comb_kernel<<<2048, 256, 0, stream>>>(o_part, l_part, xn);
    oproj_kernel<<<dim3(64, 4), 256, 0, stream>>>(xn, wbf + 3 * 262144, bo, out);
}